// Round 1
// baseline (74.216 us; speedup 1.0000x reference)
//
#include <hip/hip_runtime.h>

// Bilinear flow warp: images [32,3,512,512] f32, flows [32,2,512,512] f32
// flows[:,0] perturbs y (rows), flows[:,1] perturbs x (cols).
// out[b,c,h,w] = bilinear(images[b,c], y=h+fy clamped, x=w+fx clamped)

__global__ __launch_bounds__(256) void warp_bilinear(
    const float* __restrict__ images,
    const float* __restrict__ flows,
    float* __restrict__ out)
{
    constexpr int B = 32, C = 3, H = 512, W = 512;
    constexpr int HW = H * W;
    constexpr int VEC = 4;

    int idx = blockIdx.x * blockDim.x + threadIdx.x;
    int p = idx * VEC;                 // flat pixel index within B*H*W
    if (p >= B * HW) return;
    int b  = p / HW;
    int hw = p - b * HW;
    int h  = hw / W;
    int w  = hw - h * W;

    // flow loads: vectorized float4 (16B/lane, coalesced)
    const float* flow_b = flows + (size_t)b * 2 * HW;
    float4 fy4 = *reinterpret_cast<const float4*>(flow_b + hw);        // channel 0 = dy
    float4 fx4 = *reinterpret_cast<const float4*>(flow_b + HW + hw);   // channel 1 = dx
    float fy[VEC] = {fy4.x, fy4.y, fy4.z, fy4.w};
    float fx[VEC] = {fx4.x, fx4.y, fx4.z, fx4.w};

    const float* img = images + (size_t)b * C * HW;
    float res[C][VEC];

#pragma unroll
    for (int j = 0; j < VEC; ++j) {
        float sx = fminf(fmaxf((float)(w + j) + fx[j], 0.0f), (float)(W - 1));
        float sy = fminf(fmaxf((float)h       + fy[j], 0.0f), (float)(H - 1));
        int x0 = (int)floorf(sx);      // >= 0 since sx clamped at 0
        int y0 = (int)floorf(sy);
        x0 = min(x0, W - 2);
        y0 = min(y0, H - 2);
        float dx = sx - (float)x0;
        float dy = sy - (float)y0;
        float wa = (1.0f - dx) * (1.0f - dy);  // (y0,x0)
        float wb = (1.0f - dx) * dy;           // (y1,x0)
        float wc = dx * (1.0f - dy);           // (y0,x1)
        float wd = dx * dy;                    // (y1,x1)
        int o00 = y0 * W + x0;
#pragma unroll
        for (int c = 0; c < C; ++c) {
            const float* base = img + c * HW + o00;
            float Ia = base[0];
            float Ic = base[1];
            float Ib = base[W];
            float Id = base[W + 1];
            res[c][j] = wa * Ia + wb * Ib + wc * Ic + wd * Id;
        }
    }

    // coalesced float4 stores, one per channel
    float* outb = out + (size_t)b * C * HW + hw;
#pragma unroll
    for (int c = 0; c < C; ++c) {
        float4 v = make_float4(res[c][0], res[c][1], res[c][2], res[c][3]);
        *reinterpret_cast<float4*>(outb + c * HW) = v;
    }
}

extern "C" void kernel_launch(void* const* d_in, const int* in_sizes, int n_in,
                              void* d_out, int out_size, void* d_ws, size_t ws_size,
                              hipStream_t stream) {
    const float* images = (const float*)d_in[0];
    const float* flows  = (const float*)d_in[1];
    float* out = (float*)d_out;

    constexpr int B = 32, H = 512, W = 512;
    constexpr int total_threads = B * H * W / 4;   // 4 pixels per thread
    dim3 block(256);
    dim3 grid((total_threads + 255) / 256);        // 8192 blocks
    hipLaunchKernelGGL(warp_bilinear, grid, block, 0, stream, images, flows, out);
}